// Round 5
// baseline (143.914 us; speedup 1.0000x reference)
//
#include <hip/hip_runtime.h>

// SSIM loss, fused, barrier-free, shuffle-free, LDS-free hot loop.
// inputs: img1,img2 f32 (16,3,512,512); out f32[16].
//
// Key ideas vs earlier rounds (which were LDS/shuffle-pipe bound):
//  * 4 windowed arrays, not 5: SSIM only needs W(x1), W(x2), W(x1*x2),
//    W(x1^2+x2^2)  (mu terms give mu1^2+mu2^2; Q=x1^2+x2^2 gives sig1+sig2).
//  * Each lane owns 8 output cols AND the 10-col halo IN REGISTER: 18
//    vertical sliding column sums per array (72 regs). Horizontal 11-window
//    is a within-lane prefix slide (no cross-lane ops at all).
//  * Halo loads are 5 overlapping float4/row/img; overlap dedups in L1
//    (same-line), no extra HBM.
//  * 42 strips x 12 rows x 48 images = 2016 waves == full 2-waves/SIMD
//    residency at ~200 VGPR. No barriers; new/old slide rows prefetched a
//    full iteration ahead; old-row re-reads are L3 hits.
// Wave shfl-reduce (cold) -> atomicAdd(double) -> finalize kernel.

namespace {
constexpr int BATCH = 16;
constexpr int CHAN  = 3;
constexpr int HDIM  = 512;
constexpr int WDIM  = 512;
constexpr int WIN   = 11;
constexpr int HO    = HDIM - WIN + 1;   // 502
constexpr int WO    = WDIM - WIN + 1;   // 502
constexpr int RPS   = 12;
constexpr int STRIPS = (HO + RPS - 1) / RPS;     // 42 (last strip: 10 rows)
constexpr int WPB   = 4;
constexpr int NTHR  = WPB * 64;
constexpr int NIMG  = BATCH * CHAN;              // 48
constexpr int NWAVE = NIMG * STRIPS;             // 2016
constexpr int NBLK  = NWAVE / WPB;               // 504
constexpr float C1F = 6.5025f;                   // (0.01*255)^2
constexpr float C2F = 58.5225f;                  // (0.03*255)^2
constexpr float INVW2 = 1.0f / 121.0f;
}

__global__ __launch_bounds__(NTHR, 2) void ssim_main(
    const float* __restrict__ g1, const float* __restrict__ g2,
    double* __restrict__ ws) {
  const int t   = threadIdx.x & 63;
  const int wv  = threadIdx.x >> 6;
  const int wid = blockIdx.x * WPB + wv;
  const int img   = wid / STRIPS;        // (b,c) pair, 0..47
  const int strip = wid % STRIPS;
  const int b   = img / CHAN;
  const int r0  = strip * RPS;
  const int r1  = min(r0 + RPS, HO);

  const int cb = 8 * t;                  // first owned output col
  // 5 float4 col-offsets covering cols cb..cb+17 (clamped in-row; lanes
  // whose clamped loads pollute s[16..17] only feed masked outputs)
  int o0 = cb, o1 = cb + 4, o2 = min(cb + 8, WDIM - 4),
      o3 = min(cb + 12, WDIM - 4), o4 = min(cb + 16, WDIM - 4);

  const float* __restrict__ p1 = g1 + (size_t)img * HDIM * WDIM;
  const float* __restrict__ p2 = g2 + (size_t)img * HDIM * WDIM;

  // vertical sliding column sums, cols cb..cb+17
  float s1[18], s2[18], sp[18], sq[18];
#pragma unroll
  for (int k = 0; k < 18; ++k) s1[k] = s2[k] = sp[k] = sq[k] = 0.f;

  // two row buffers (A: "new" row; B: "old" row in the main loop)
  float uA[20], vA[20], uB[20], vB[20];

  auto loadrow = [&](int row, float* U, float* V) {
    const float* q1 = p1 + (size_t)row * WDIM;
    const float* q2 = p2 + (size_t)row * WDIM;
    *(float4*)(U + 0)  = *(const float4*)(q1 + o0);
    *(float4*)(U + 4)  = *(const float4*)(q1 + o1);
    *(float4*)(U + 8)  = *(const float4*)(q1 + o2);
    *(float4*)(U + 12) = *(const float4*)(q1 + o3);
    *(float4*)(U + 16) = *(const float4*)(q1 + o4);
    *(float4*)(V + 0)  = *(const float4*)(q2 + o0);
    *(float4*)(V + 4)  = *(const float4*)(q2 + o1);
    *(float4*)(V + 8)  = *(const float4*)(q2 + o2);
    *(float4*)(V + 12) = *(const float4*)(q2 + o3);
    *(float4*)(V + 16) = *(const float4*)(q2 + o4);
  };

  auto accum = [&](const float* U, const float* V) {
#pragma unroll
    for (int k = 0; k < 18; ++k) {
      float x = U[k], y = V[k];
      s1[k] += x;
      s2[k] += y;
      sp[k] = fmaf(x, y, sp[k]);
      sq[k] = fmaf(x, x, sq[k]);
      sq[k] = fmaf(y, y, sq[k]);
    }
  };
  auto desum = [&](const float* U, const float* V) {
#pragma unroll
    for (int k = 0; k < 18; ++k) {
      float x = U[k], y = V[k];
      s1[k] -= x;
      s2[k] -= y;
      sp[k] = fmaf(x, -y, sp[k]);
      sq[k] = fmaf(x, -x, sq[k]);
      sq[k] = fmaf(y, -y, sq[k]);
    }
  };

  // within-lane horizontal 11-window: prefix slide over the 18 col sums
  auto hwin = [&](const float* s, float* W) {
    float w = ((s[0] + s[1]) + (s[2] + s[3])) + ((s[4] + s[5]) + (s[6] + s[7]))
            + ((s[8] + s[9]) + s[10]);
    W[0] = w;
#pragma unroll
    for (int j = 1; j < 8; ++j) {
      w = (w - s[j - 1]) + s[j + 10];
      W[j] = w;
    }
  };

  // ---- warm-up: accumulate rows r0 .. r0+9 (2-deep pipelined) ----
  loadrow(r0,     uA, vA);
  loadrow(r0 + 1, uB, vB);
#pragma unroll
  for (int dy = 0; dy < 10; dy += 2) {
    accum(uA, vA);
    loadrow(r0 + dy + 2, uA, vA);   // dy=8 loads row r0+10 -> NEW
    accum(uB, vB);
    if (dy < 8) loadrow(r0 + dy + 3, uB, vB);
  }
  loadrow(r0, uB, vB);              // OLD = row r0

  // ---- main loop: one output row per iteration ----
  float acc = 0.f;
  for (int r = r0; r < r1; ++r) {
    accum(uA, vA);                               // window = rows [r, r+10]
    loadrow(min(r + WIN, HDIM - 1), uA, vA);     // prefetch next NEW early

    float W1[8], W2[8], WP[8], WQ[8];
    hwin(s1, W1);
    hwin(s2, W2);
    hwin(sp, WP);
    hwin(sq, WQ);

#pragma unroll
    for (int j = 0; j < 8; ++j) {
      float mu1 = W1[j] * INVW2, mu2 = W2[j] * INVW2;
      float mu12 = mu1 * mu2;
      float msq  = fmaf(mu1, mu1, mu2 * mu2);
      float sg12 = fmaf(WP[j], INVW2, -mu12);       // sigma12
      float sgq  = fmaf(WQ[j], INVW2, -msq);        // sigma1+sigma2
      float n = fmaf(2.f, mu12, C1F) * fmaf(2.f, sg12, C2F);
      float d = (msq + C1F) * (sgq + C2F);
      float val = n * __builtin_amdgcn_rcpf(d);     // 1-ulp; thr 6e-5
      acc += (cb + j < WO) ? val : 0.f;
    }

    desum(uB, vB);                               // slide out row r
    loadrow(min(r + 1, HDIM - 1), uB, vB);       // prefetch next OLD
  }

  // wave reduction (cold path), one double atomic per wave
#pragma unroll
  for (int off = 32; off > 0; off >>= 1) acc += __shfl_down(acc, off, 64);
  if (t == 0) atomicAdd(&ws[b], (double)acc);
}

__global__ void ssim_finalize(const double* __restrict__ ws,
                              float* __restrict__ out) {
  int i = threadIdx.x;
  if (i < BATCH) {
    double mean = ws[i] / ((double)CHAN * HO * WO);
    out[i] = (float)(1.0 - mean);
  }
}

extern "C" void kernel_launch(void* const* d_in, const int* in_sizes, int n_in,
                              void* d_out, int out_size, void* d_ws,
                              size_t ws_size, hipStream_t stream) {
  const float* img1 = (const float*)d_in[0];
  const float* img2 = (const float*)d_in[1];
  float* out = (float*)d_out;
  double* ws = (double*)d_ws;

  hipMemsetAsync(d_ws, 0, BATCH * sizeof(double), stream);
  ssim_main<<<dim3(NBLK), NTHR, 0, stream>>>(img1, img2, ws);
  ssim_finalize<<<1, 64, 0, stream>>>(ws, out);
}

// Round 6
// 87.414 us; speedup vs baseline: 1.6464x; 1.6464x over previous
//
#include <hip/hip_runtime.h>

// SSIM loss, fused, barrier-free, LDS-free. in: f32 (16,3,512,512)x2; out f32[16].
//
// Structure = round-4 (1 wave owns a full 512-col row strip, 8 cols/lane,
// vertical sliding column sums in registers, horizontal 11-window via
// cross-lane shuffles) with the latency/occupancy fixes:
//  * RPS=5 -> 101 strips x 48 images = 4848 waves (2.4x round-4 TLP).
//  * 4 sum arrays not 5: W(x1), W(x2), W(x1*x2), W(x1^2+x2^2) suffice
//    (SSIM uses only mu1^2+mu2^2 and sig1+sig2). 32 sum regs.
//  * Horizontal window: running slide W_j = W_{j-1} - s[j-1] + H[j+2],
//    H[0..7]=shfl_down(s,1), H[8..9]=shfl_down(s[0..1],2) — 10 independent
//    shuffles per array, H consumed per-array (small live set, no spill).
//  * NEW row prefetched a full iteration ahead (HBM latency); OLD row
//    issued at top of iteration, consumed ~400cy later (L3 hit).
// Register budget ~110 VGPR -> 4 waves/SIMD, zero scratch (round-5 lesson).

namespace {
constexpr int BATCH = 16;
constexpr int CHAN  = 3;
constexpr int HDIM  = 512;
constexpr int WDIM  = 512;
constexpr int WIN   = 11;
constexpr int HO    = HDIM - WIN + 1;   // 502
constexpr int WO    = WDIM - WIN + 1;   // 502
constexpr int RPS   = 5;
constexpr int STRIPS = (HO + RPS - 1) / RPS;     // 101 (last strip: 2 rows)
constexpr int WPB   = 4;
constexpr int NTHR  = WPB * 64;
constexpr int NWAVE = BATCH * CHAN * STRIPS;     // 4848
constexpr int NBLK  = NWAVE / WPB;               // 1212
constexpr float C1F = 6.5025f;                   // (0.01*255)^2
constexpr float C2F = 58.5225f;                  // (0.03*255)^2
constexpr float INVW2 = 1.0f / 121.0f;
}

__global__ __launch_bounds__(NTHR) void ssim_main(
    const float* __restrict__ g1, const float* __restrict__ g2,
    double* __restrict__ ws) {
  const int t   = threadIdx.x & 63;
  const int wv  = threadIdx.x >> 6;
  const int wid = blockIdx.x * WPB + wv;
  const int img   = wid / STRIPS;        // (b,c) pair, 0..47
  const int strip = wid % STRIPS;
  const int b   = img / CHAN;
  const int r0  = strip * RPS;
  const int r1  = min(r0 + RPS, HO);

  const int cb = 8 * t;                  // first owned col
  const float* __restrict__ p1 = g1 + (size_t)img * HDIM * WDIM + cb;
  const float* __restrict__ p2 = g2 + (size_t)img * HDIM * WDIM + cb;

  // vertical sliding column sums for this lane's 8 columns
  float s1[8], s2[8], sp[8], sq[8];
#pragma unroll
  for (int k = 0; k < 8; ++k) s1[k] = s2[k] = sp[k] = sq[k] = 0.f;

  auto accum = [&](const float4& U0, const float4& U1, const float4& V0,
                   const float4& V1) {
    float uu[8] = {U0.x, U0.y, U0.z, U0.w, U1.x, U1.y, U1.z, U1.w};
    float vv[8] = {V0.x, V0.y, V0.z, V0.w, V1.x, V1.y, V1.z, V1.w};
#pragma unroll
    for (int k = 0; k < 8; ++k) {
      float x = uu[k], y = vv[k];
      s1[k] += x;
      s2[k] += y;
      sp[k] = fmaf(x, y, sp[k]);
      sq[k] = fmaf(x, x, sq[k]);
      sq[k] = fmaf(y, y, sq[k]);
    }
  };
  auto desum = [&](const float4& U0, const float4& U1, const float4& V0,
                   const float4& V1) {
    float uu[8] = {U0.x, U0.y, U0.z, U0.w, U1.x, U1.y, U1.z, U1.w};
    float vv[8] = {V0.x, V0.y, V0.z, V0.w, V1.x, V1.y, V1.z, V1.w};
#pragma unroll
    for (int k = 0; k < 8; ++k) {
      float x = uu[k], y = vv[k];
      s1[k] -= x;
      s2[k] -= y;
      sp[k] = fmaf(x, -y, sp[k]);
      sq[k] = fmaf(x, -x, sq[k]);
      sq[k] = fmaf(y, -y, sq[k]);
    }
  };

  // windows for one array: 10 independent shuffles + running slide.
  // H[j] = colsum(cb+8+j): H[0..7]=sh1(s[0..7]), H[8..9]=sh2(s[0..1]).
  auto hwin = [&](const float s[8], float* W) {
    float H0 = __shfl_down(s[0], 1, 64), H1 = __shfl_down(s[1], 1, 64);
    float H2 = __shfl_down(s[2], 1, 64), H3 = __shfl_down(s[3], 1, 64);
    float H4 = __shfl_down(s[4], 1, 64), H5 = __shfl_down(s[5], 1, 64);
    float H6 = __shfl_down(s[6], 1, 64), H7 = __shfl_down(s[7], 1, 64);
    float H8 = __shfl_down(s[0], 2, 64), H9 = __shfl_down(s[1], 2, 64);
    float w = (((s[0] + s[1]) + (s[2] + s[3])) +
               ((s[4] + s[5]) + (s[6] + s[7]))) + ((H0 + H1) + H2);
    W[0] = w;
    w = (w - s[0]) + H3;  W[1] = w;
    w = (w - s[1]) + H4;  W[2] = w;
    w = (w - s[2]) + H5;  W[3] = w;
    w = (w - s[3]) + H6;  W[4] = w;
    w = (w - s[4]) + H7;  W[5] = w;
    w = (w - s[5]) + H8;  W[6] = w;
    w = (w - s[6]) + H9;  W[7] = w;
  };

  // ---- warm-up: rows r0 .. r0+9, 2-deep pipelined ----
  float4 au0, au1, av0, av1, bu0, bu1, bv0, bv1;
  auto loadA = [&](int row) {
    const float* q1 = p1 + (size_t)row * WDIM;
    const float* q2 = p2 + (size_t)row * WDIM;
    au0 = *(const float4*)q1; au1 = *(const float4*)(q1 + 4);
    av0 = *(const float4*)q2; av1 = *(const float4*)(q2 + 4);
  };
  auto loadB = [&](int row) {
    const float* q1 = p1 + (size_t)row * WDIM;
    const float* q2 = p2 + (size_t)row * WDIM;
    bu0 = *(const float4*)q1; bu1 = *(const float4*)(q1 + 4);
    bv0 = *(const float4*)q2; bv1 = *(const float4*)(q2 + 4);
  };

  loadA(r0);
  loadB(r0 + 1);
#pragma unroll
  for (int dy = 0; dy < 10; dy += 2) {
    accum(au0, au1, av0, av1);
    loadA(r0 + dy + 2);                 // dy=8 loads row r0+10 -> NEW
    accum(bu0, bu1, bv0, bv1);
    if (dy < 8) loadB(r0 + dy + 3);
  }

  // ---- main loop: A = NEW (row r+10), B = OLD (row r) ----
  float acc = 0.f;
  for (int r = r0; r < r1; ++r) {
    accum(au0, au1, av0, av1);               // window = rows [r, r+10]
    loadA(min(r + WIN, HDIM - 1));           // prefetch next NEW (HBM-deep)
    loadB(r);                                // OLD row (L3 hit), used below

    float W1[8], W2[8], WP[8], WQ[8];
    hwin(s1, W1);
    hwin(s2, W2);
    hwin(sp, WP);
    hwin(sq, WQ);

#pragma unroll
    for (int j = 0; j < 8; ++j) {
      float mu1 = W1[j] * INVW2, mu2 = W2[j] * INVW2;
      float mu12 = mu1 * mu2;
      float msq  = fmaf(mu1, mu1, mu2 * mu2);
      float sg12 = fmaf(WP[j], INVW2, -mu12);     // sigma12
      float sgq  = fmaf(WQ[j], INVW2, -msq);      // sigma1+sigma2
      float n = fmaf(2.f, mu12, C1F) * fmaf(2.f, sg12, C2F);
      float d = (msq + C1F) * (sgq + C2F);
      float val = n * __builtin_amdgcn_rcpf(d);   // 1-ulp; thr 6e-5
      if (cb + j < WO) acc += val;
    }

    desum(bu0, bu1, bv0, bv1);               // slide out row r
  }

  // wave reduction (cold), one double atomic per wave
#pragma unroll
  for (int off = 32; off > 0; off >>= 1) acc += __shfl_down(acc, off, 64);
  if (t == 0) atomicAdd(&ws[b], (double)acc);
}

__global__ void ssim_finalize(const double* __restrict__ ws,
                              float* __restrict__ out) {
  int i = threadIdx.x;
  if (i < BATCH) {
    double mean = ws[i] / ((double)CHAN * HO * WO);
    out[i] = (float)(1.0 - mean);
  }
}

extern "C" void kernel_launch(void* const* d_in, const int* in_sizes, int n_in,
                              void* d_out, int out_size, void* d_ws,
                              size_t ws_size, hipStream_t stream) {
  const float* img1 = (const float*)d_in[0];
  const float* img2 = (const float*)d_in[1];
  float* out = (float*)d_out;
  double* ws = (double*)d_ws;

  hipMemsetAsync(d_ws, 0, BATCH * sizeof(double), stream);
  ssim_main<<<dim3(NBLK), NTHR, 0, stream>>>(img1, img2, ws);
  ssim_finalize<<<1, 64, 0, stream>>>(ws, out);
}

// Round 7
// 66.627 us; speedup vs baseline: 2.1600x; 1.3120x over previous
//
#include <hip/hip_runtime.h>

// SSIM loss, fused. in: f32 (16,3,512,512) x2; out: f32[16].
//
// Structure: 1 wave owns a 512-col x RPS-row strip, 8 cols/lane. Vertical
// sliding 11-row column sums {s1,s2,s1*s2-sum,sq=s1^2+s2^2-sum} kept in
// REGISTERS for the lane's own 8 cols. Per output row:
//   * lane writes its 8 cols' quantity-quads to wave-private LDS as 8x
//     ds_write_b128, sigma-permuted layout sigma(c)=(c&7)*64+(c>>3) so both
//     writes (fixed i: consecutive lanes -> consecutive 16B) and halo reads
//     are conflict-free;
//   * lane reads only the 10 halo col-quads (cols 8t+8..8t+17) as b128;
//     window slide W_j = W_{j-1} - own[j-1](registers!) + lds[8t+j+10];
//   * SSIM per pixel (rcp), per-lane acc.
// No __syncthreads (wave-private LDS + lgkmcnt). NEW row (r+11) and OLD row
// (r+1) prefetched a full iteration ahead (~900cy cover). Old-row re-reads
// are L3 hits. Wave shfl-reduce -> atomicAdd(double) -> finalize.
// Register budget ~130 VGPR; spill check = WRITE_SIZE ~ 0 (round-5 lesson).

namespace {
constexpr int BATCH = 16;
constexpr int CHAN  = 3;
constexpr int HDIM  = 512;
constexpr int WDIM  = 512;
constexpr int WIN   = 11;
constexpr int HO    = HDIM - WIN + 1;   // 502
constexpr int WO    = WDIM - WIN + 1;   // 502
constexpr int RPS   = 8;
constexpr int STRIPS = (HO + RPS - 1) / RPS;     // 63 (last strip: 6 rows)
constexpr int WPB   = 4;                          // waves per block
constexpr int NTHR  = WPB * 64;
constexpr int NWAVE = BATCH * CHAN * STRIPS;      // 3024
constexpr int NBLK  = NWAVE / WPB;                // 756
constexpr float C1F = 6.5025f;                    // (0.01*255)^2
constexpr float C2F = 58.5225f;                   // (0.03*255)^2
constexpr float INVW2 = 1.0f / 121.0f;
// per-wave LDS: 512 quads + spill-over pad for lane63 reads (t+2 -> +66)
constexpr int QPW = 512;                          // quads per wave
constexpr int LDSQ = WPB * QPW + 9 * 64 + 66;     // padded total quads
}

__global__ __launch_bounds__(NTHR) void ssim_main(
    const float* __restrict__ g1, const float* __restrict__ g2,
    double* __restrict__ ws) {
  __shared__ float4 lds4[LDSQ];

  const int t   = threadIdx.x & 63;
  const int wv  = threadIdx.x >> 6;
  const int wid = blockIdx.x * WPB + wv;
  const int img   = wid / STRIPS;        // (b,c) pair, 0..47
  const int strip = wid % STRIPS;
  const int b   = img / CHAN;
  const int r0  = strip * RPS;
  const int r1  = min(r0 + RPS, HO);

  const int cb = 8 * t;                  // first owned col
  float4* __restrict__ W  = lds4 + wv * QPW;        // write base (own cols)
  const float4* __restrict__ Rd = lds4 + wv * QPW;  // read base

  const float* __restrict__ p1 = g1 + (size_t)img * HDIM * WDIM + cb;
  const float* __restrict__ p2 = g2 + (size_t)img * HDIM * WDIM + cb;

  // vertical sliding column sums for the lane's own 8 columns
  float s1[8], s2[8], sp[8], sq[8];
#pragma unroll
  for (int k = 0; k < 8; ++k) s1[k] = s2[k] = sp[k] = sq[k] = 0.f;

  // row buffers: A = NEW row, B = OLD row
  float4 au0, au1, av0, av1, bu0, bu1, bv0, bv1;
  auto loadA = [&](int row) {
    const float* q1 = p1 + (size_t)row * WDIM;
    const float* q2 = p2 + (size_t)row * WDIM;
    au0 = *(const float4*)q1; au1 = *(const float4*)(q1 + 4);
    av0 = *(const float4*)q2; av1 = *(const float4*)(q2 + 4);
  };
  auto loadB = [&](int row) {
    const float* q1 = p1 + (size_t)row * WDIM;
    const float* q2 = p2 + (size_t)row * WDIM;
    bu0 = *(const float4*)q1; bu1 = *(const float4*)(q1 + 4);
    bv0 = *(const float4*)q2; bv1 = *(const float4*)(q2 + 4);
  };
  auto accum = [&]() {
    float uu[8] = {au0.x, au0.y, au0.z, au0.w, au1.x, au1.y, au1.z, au1.w};
    float vv[8] = {av0.x, av0.y, av0.z, av0.w, av1.x, av1.y, av1.z, av1.w};
#pragma unroll
    for (int k = 0; k < 8; ++k) {
      float x = uu[k], y = vv[k];
      s1[k] += x;
      s2[k] += y;
      sp[k] = fmaf(x, y, sp[k]);
      sq[k] = fmaf(x, x, sq[k]);
      sq[k] = fmaf(y, y, sq[k]);
    }
  };
  auto desum = [&]() {
    float uu[8] = {bu0.x, bu0.y, bu0.z, bu0.w, bu1.x, bu1.y, bu1.z, bu1.w};
    float vv[8] = {bv0.x, bv0.y, bv0.z, bv0.w, bv1.x, bv1.y, bv1.z, bv1.w};
#pragma unroll
    for (int k = 0; k < 8; ++k) {
      float x = uu[k], y = vv[k];
      s1[k] -= x;
      s2[k] -= y;
      sp[k] = fmaf(x, -y, sp[k]);
      sq[k] = fmaf(x, -x, sq[k]);
      sq[k] = fmaf(y, -y, sq[k]);
    }
  };

  // ---- warm-up: accumulate rows r0 .. r0+9, 2-deep pipelined ----
  loadA(r0);
  loadB(r0 + 1);
#pragma unroll
  for (int dy = 0; dy < 10; dy += 2) {
    accum();                 // row r0+dy (from A)
    loadA(r0 + dy + 2);      // dy=8 -> loads row r0+10 = first NEW
    // fold B into sums (row r0+dy+1)
    { float4 tu0 = au0, tu1 = au1, tv0 = av0, tv1 = av1;
      au0 = bu0; au1 = bu1; av0 = bv0; av1 = bv1;
      accum();
      au0 = tu0; au1 = tu1; av0 = tv0; av1 = tv1; }
    if (dy < 8) loadB(r0 + dy + 3);
  }
  loadB(r0);                 // first OLD row

  // ---- main loop ----
  float acc = 0.f;
  for (int r = r0; r < r1; ++r) {
    accum();                              // window = rows [r, r+10]
    loadA(min(r + WIN, HDIM - 1));        // prefetch next NEW (full-iter cover)

    // publish own 8 col-quads: sigma(8t+i) = i*64 + t  -> conflict-free
#pragma unroll
    for (int i = 0; i < 8; ++i)
      W[i * 64 + t] = make_float4(s1[i], s2[i], sp[i], sq[i]);
    asm volatile("s_waitcnt lgkmcnt(0)" ::: "memory");

    // halo reads: cols 8t+8+m -> m<8: quad m*64 + (t+1); m=8,9: (m-8)*64+(t+2)
    float4 cN[10];
#pragma unroll
    for (int m = 0; m < 8; ++m) cN[m] = Rd[m * 64 + t + 1];
    cN[8] = Rd[t + 2];
    cN[9] = Rd[64 + t + 2];

    // W_0 = sum(own 0..7) + cols +8,+9,+10
    float w1 = ((s1[0] + s1[1]) + (s1[2] + s1[3])) +
               ((s1[4] + s1[5]) + (s1[6] + s1[7])) +
               ((cN[0].x + cN[1].x) + cN[2].x);
    float w2 = ((s2[0] + s2[1]) + (s2[2] + s2[3])) +
               ((s2[4] + s2[5]) + (s2[6] + s2[7])) +
               ((cN[0].y + cN[1].y) + cN[2].y);
    float wp = ((sp[0] + sp[1]) + (sp[2] + sp[3])) +
               ((sp[4] + sp[5]) + (sp[6] + sp[7])) +
               ((cN[0].z + cN[1].z) + cN[2].z);
    float wq = ((sq[0] + sq[1]) + (sq[2] + sq[3])) +
               ((sq[4] + sq[5]) + (sq[6] + sq[7])) +
               ((cN[0].w + cN[1].w) + cN[2].w);

#pragma unroll
    for (int j = 0; j < 8; ++j) {
      if (j > 0) {  // slide: drop own col j-1, add halo col 8t+j+10
        w1 = (w1 - s1[j - 1]) + cN[j + 2].x;
        w2 = (w2 - s2[j - 1]) + cN[j + 2].y;
        wp = (wp - sp[j - 1]) + cN[j + 2].z;
        wq = (wq - sq[j - 1]) + cN[j + 2].w;
      }
      float mu1 = w1 * INVW2, mu2 = w2 * INVW2;
      float mu12 = mu1 * mu2;
      float msq  = fmaf(mu1, mu1, mu2 * mu2);
      float sg12 = fmaf(wp, INVW2, -mu12);      // sigma12
      float sgq  = fmaf(wq, INVW2, -msq);       // sigma1+sigma2
      float n = fmaf(2.f, mu12, C1F) * fmaf(2.f, sg12, C2F);
      float d = (msq + C1F) * (sgq + C2F);
      float val = n * __builtin_amdgcn_rcpf(d); // 1-ulp; thr 6e-5
      if (cb + j < WO) acc += val;
    }

    desum();                              // slide out row r (from B)
    loadB(r + 1);                         // prefetch next OLD (L3 hit)
  }

  // wave reduction (cold), one double atomic per wave
#pragma unroll
  for (int off = 32; off > 0; off >>= 1) acc += __shfl_down(acc, off, 64);
  if (t == 0) atomicAdd(&ws[b], (double)acc);
}

__global__ void ssim_finalize(const double* __restrict__ ws,
                              float* __restrict__ out) {
  int i = threadIdx.x;
  if (i < BATCH) {
    double mean = ws[i] / ((double)CHAN * HO * WO);
    out[i] = (float)(1.0 - mean);
  }
}

extern "C" void kernel_launch(void* const* d_in, const int* in_sizes, int n_in,
                              void* d_out, int out_size, void* d_ws,
                              size_t ws_size, hipStream_t stream) {
  const float* img1 = (const float*)d_in[0];
  const float* img2 = (const float*)d_in[1];
  float* out = (float*)d_out;
  double* ws = (double*)d_ws;

  hipMemsetAsync(d_ws, 0, BATCH * sizeof(double), stream);
  ssim_main<<<dim3(NBLK), NTHR, 0, stream>>>(img1, img2, ws);
  ssim_finalize<<<1, 64, 0, stream>>>(ws, out);
}

// Round 8
// 62.083 us; speedup vs baseline: 2.3181x; 1.0732x over previous
//
#include <hip/hip_runtime.h>

// SSIM loss, fused. in: f32 (16,3,512,512) x2; out: f32[16].
//
// 1 wave owns a 512-col x RPS-row strip, 8 cols/lane. Vertical sliding
// 11-row column sums {s1,s2,sp=sum(x1*x2),sq=sum(x1^2+x2^2)} in REGISTERS.
// Per output row: 8x ds_write_b128 of own col-quads into sigma-permuted
// wave-private LDS (sigma(8t+i)=i*64+t: writes AND halo reads conflict-free),
// 10x ds_read_b128 halo (cols 8t+8..8t+17, lane-wrapped: wrapped lanes only
// feed masked outputs); window slide uses own sums from registers.
// No __syncthreads anywhere. NEW row (r+11) prefetched a full iteration
// ahead; OLD row re-reads hit L2/L3. Banked double atomics (256 slots).
//
// Round-7 lesson: LDS pad blew blocks to 43.5KB and grid to 756 -> 15%
// occupancy. Now: exactly 32KB/block, 1212 blocks, VGPR-capped 16 waves/CU.

namespace {
constexpr int BATCH = 16;
constexpr int CHAN  = 3;
constexpr int HDIM  = 512;
constexpr int WDIM  = 512;
constexpr int WIN   = 11;
constexpr int HO    = HDIM - WIN + 1;   // 502
constexpr int WO    = WDIM - WIN + 1;   // 502
constexpr int RPS   = 5;
constexpr int STRIPS = (HO + RPS - 1) / RPS;     // 101 (last strip: 2 rows)
constexpr int WPB   = 4;                          // waves per block
constexpr int NTHR  = WPB * 64;
constexpr int NWAVE = BATCH * CHAN * STRIPS;      // 4848
constexpr int NBLK  = NWAVE / WPB;                // 1212
constexpr int NBANK = 16;                         // atomic banks per batch-img
// scale-folded constants: C*121^2 (121^4 cancels in n/d)
constexpr float K1 = 6.5025f  * 14641.0f;         // C1*121^2
constexpr float K2 = 58.5225f * 14641.0f;         // C2*121^2
constexpr float W2F = 121.0f;
}

__global__ __launch_bounds__(NTHR) void ssim_main(
    const float* __restrict__ g1, const float* __restrict__ g2,
    double* __restrict__ ws) {
  __shared__ float4 lds4[WPB * 512];               // 32 KB exactly

  const int t   = threadIdx.x & 63;
  const int wv  = threadIdx.x >> 6;
  const int wid = blockIdx.x * WPB + wv;
  const int img   = wid / STRIPS;        // (b,c) pair, 0..47
  const int strip = wid % STRIPS;
  const int b   = img / CHAN;
  const int r0  = strip * RPS;
  const int r1  = min(r0 + RPS, HO);

  const int cb = 8 * t;                  // first owned col
  float4* __restrict__ W  = lds4 + wv * 512;
  const float4* __restrict__ Rd = lds4 + wv * 512;
  const int tp1 = (t + 1) & 63;          // halo lanes (wrap: masked outputs)
  const int tp2 = (t + 2) & 63;

  const float* __restrict__ p1 = g1 + (size_t)img * HDIM * WDIM + cb;
  const float* __restrict__ p2 = g2 + (size_t)img * HDIM * WDIM + cb;

  // vertical sliding column sums for the lane's own 8 columns
  float s1[8], s2[8], sp[8], sq[8];
#pragma unroll
  for (int k = 0; k < 8; ++k) s1[k] = s2[k] = sp[k] = sq[k] = 0.f;

  // row buffers: A = NEW row, B = OLD row
  float4 au0, au1, av0, av1, bu0, bu1, bv0, bv1;
  auto loadA = [&](int row) {
    const float* q1 = p1 + (size_t)row * WDIM;
    const float* q2 = p2 + (size_t)row * WDIM;
    au0 = *(const float4*)q1; au1 = *(const float4*)(q1 + 4);
    av0 = *(const float4*)q2; av1 = *(const float4*)(q2 + 4);
  };
  auto loadB = [&](int row) {
    const float* q1 = p1 + (size_t)row * WDIM;
    const float* q2 = p2 + (size_t)row * WDIM;
    bu0 = *(const float4*)q1; bu1 = *(const float4*)(q1 + 4);
    bv0 = *(const float4*)q2; bv1 = *(const float4*)(q2 + 4);
  };
  auto accum = [&]() {
    float uu[8] = {au0.x, au0.y, au0.z, au0.w, au1.x, au1.y, au1.z, au1.w};
    float vv[8] = {av0.x, av0.y, av0.z, av0.w, av1.x, av1.y, av1.z, av1.w};
#pragma unroll
    for (int k = 0; k < 8; ++k) {
      float x = uu[k], y = vv[k];
      s1[k] += x;
      s2[k] += y;
      sp[k] = fmaf(x, y, sp[k]);
      sq[k] = fmaf(x, x, sq[k]);
      sq[k] = fmaf(y, y, sq[k]);
    }
  };
  auto desum = [&]() {
    float uu[8] = {bu0.x, bu0.y, bu0.z, bu0.w, bu1.x, bu1.y, bu1.z, bu1.w};
    float vv[8] = {bv0.x, bv0.y, bv0.z, bv0.w, bv1.x, bv1.y, bv1.z, bv1.w};
#pragma unroll
    for (int k = 0; k < 8; ++k) {
      float x = uu[k], y = vv[k];
      s1[k] -= x;
      s2[k] -= y;
      sp[k] = fmaf(x, -y, sp[k]);
      sq[k] = fmaf(x, -x, sq[k]);
      sq[k] = fmaf(y, -y, sq[k]);
    }
  };

  // ---- warm-up: accumulate rows r0 .. r0+9, 2-deep pipelined ----
  loadA(r0);
  loadB(r0 + 1);
#pragma unroll
  for (int dy = 0; dy < 10; dy += 2) {
    accum();                 // row r0+dy
    loadA(r0 + dy + 2);      // dy=8 -> loads row r0+10 = first NEW
    { float4 tu0 = au0, tu1 = au1, tv0 = av0, tv1 = av1;
      au0 = bu0; au1 = bu1; av0 = bv0; av1 = bv1;
      accum();               // row r0+dy+1
      au0 = tu0; au1 = tu1; av0 = tv0; av1 = tv1; }
    if (dy < 8) loadB(r0 + dy + 3);
  }
  loadB(r0);                 // first OLD row

  // ---- main loop ----
  float acc = 0.f;
  for (int r = r0; r < r1; ++r) {
    accum();                              // window = rows [r, r+10]
    loadA(min(r + WIN, HDIM - 1));        // prefetch next NEW (full-iter cover)

    // publish own 8 col-quads (conflict-free: consecutive lanes contiguous)
#pragma unroll
    for (int i = 0; i < 8; ++i)
      W[i * 64 + t] = make_float4(s1[i], s2[i], sp[i], sq[i]);
    asm volatile("s_waitcnt lgkmcnt(0)" ::: "memory");

    // halo: cols cb+8+m. m<8: quad m*64+(t+1); m=8,9: (m-8)*64+(t+2)
    float4 cN[10];
#pragma unroll
    for (int m = 0; m < 8; ++m) cN[m] = Rd[m * 64 + tp1];
    cN[8] = Rd[tp2];
    cN[9] = Rd[64 + tp2];

    // first window (cols cb..cb+10), raw sums
    float w1 = ((s1[0] + s1[1]) + (s1[2] + s1[3])) +
               ((s1[4] + s1[5]) + (s1[6] + s1[7])) +
               ((cN[0].x + cN[1].x) + cN[2].x);
    float w2 = ((s2[0] + s2[1]) + (s2[2] + s2[3])) +
               ((s2[4] + s2[5]) + (s2[6] + s2[7])) +
               ((cN[0].y + cN[1].y) + cN[2].y);
    float wp = ((sp[0] + sp[1]) + (sp[2] + sp[3])) +
               ((sp[4] + sp[5]) + (sp[6] + sp[7])) +
               ((cN[0].z + cN[1].z) + cN[2].z);
    float wq = ((sq[0] + sq[1]) + (sq[2] + sq[3])) +
               ((sq[4] + sq[5]) + (sq[6] + sq[7])) +
               ((cN[0].w + cN[1].w) + cN[2].w);

#pragma unroll
    for (int j = 0; j < 8; ++j) {
      if (j > 0) {  // slide: drop own col j-1 (regs), add halo col cb+j+10
        w1 = (w1 - s1[j - 1]) + cN[j + 2].x;
        w2 = (w2 - s2[j - 1]) + cN[j + 2].y;
        wp = (wp - sp[j - 1]) + cN[j + 2].z;
        wq = (wq - sq[j - 1]) + cN[j + 2].w;
      }
      // scale-folded SSIM: n*121^4 / d*121^4 (121^4 cancels)
      float s12  = w1 * w2;
      float msq  = fmaf(w1, w1, w2 * w2);
      float N1   = fmaf(2.f, s12, K1);
      float N2   = fmaf(2.f, fmaf(W2F, wp, -s12), K2);
      float D1   = msq + K1;
      float D2   = fmaf(W2F, wq, -msq) + K2;
      float val  = (N1 * N2) * __builtin_amdgcn_rcpf(D1 * D2);
      acc += (cb + j < WO) ? val : 0.f;
    }

    desum();                              // slide out row r
    loadB(r + 1);                         // prefetch next OLD (L2/L3 hit)
  }

  // wave reduction (cold), banked double atomic (spread 256 slots)
#pragma unroll
  for (int off = 32; off > 0; off >>= 1) acc += __shfl_down(acc, off, 64);
  if (t == 0) atomicAdd(&ws[b * NBANK + (wid & (NBANK - 1))], (double)acc);
}

__global__ void ssim_finalize(const double* __restrict__ ws,
                              float* __restrict__ out) {
  int i = threadIdx.x;
  if (i < BATCH) {
    double s = 0.0;
#pragma unroll
    for (int k = 0; k < NBANK; ++k) s += ws[i * NBANK + k];
    out[i] = (float)(1.0 - s / ((double)CHAN * HO * WO));
  }
}

extern "C" void kernel_launch(void* const* d_in, const int* in_sizes, int n_in,
                              void* d_out, int out_size, void* d_ws,
                              size_t ws_size, hipStream_t stream) {
  const float* img1 = (const float*)d_in[0];
  const float* img2 = (const float*)d_in[1];
  float* out = (float*)d_out;
  double* ws = (double*)d_ws;

  hipMemsetAsync(d_ws, 0, BATCH * NBANK * sizeof(double), stream);
  ssim_main<<<dim3(NBLK), NTHR, 0, stream>>>(img1, img2, ws);
  ssim_finalize<<<1, 64, 0, stream>>>(ws, out);
}